// Round 1
// baseline (1496.962 us; speedup 1.0000x reference)
//
#include <hip/hip_runtime.h>
#include <hip/hip_bf16.h>
#include <math.h>

// Problem constants (from reference)
#define B_   16
#define D_   512
#define T_   2048
#define K_   8
#define C_   1024
#define CH_  64
#define NQ_  (B_ * K_ * T_)        // 262144 queries
#define NEL_ (B_ * D_ * T_)        // 16777216 quantized elements
#define QOFF 16777216              // out offset: [quantized | commit | ppl[8]]

// ws layout:
//   [0, 32768)      float halfcnorm[K_*C_]   (0.5*||c||^2)
//   [32768, 65536)  int   counts[K_*C_]
//   [65536, 65544)  double sse
#define WS_HCN   0
#define WS_CNT   32768
#define WS_SSE   65536

// ---------------------------------------------------------------------------
// Kernel A: halfcnorm[k*C + c] = 0.5 * sum_ch cb[k][c][ch]^2
// ---------------------------------------------------------------------------
__global__ void vq_cnorm(const float* __restrict__ cb, float* __restrict__ hcn) {
    int i = blockIdx.x * 256 + threadIdx.x;   // 0 .. K_*C_-1
    const float4* r = (const float4*)(cb + (size_t)i * CH_);
    float s = 0.f;
#pragma unroll
    for (int j = 0; j < CH_ / 4; ++j) {
        float4 v = r[j];
        s = fmaf(v.x, v.x, s);
        s = fmaf(v.y, v.y, s);
        s = fmaf(v.z, v.z, s);
        s = fmaf(v.w, v.w, s);
    }
    hcn[i] = 0.5f * s;
}

// ---------------------------------------------------------------------------
// Kernel B: main — distances, top-2 argmin (fp32) + fp64 rescore, quantized
// write, SSE accumulation, histogram.
// grid = B_*K_*(T_/256) = 1024 blocks of 256 threads; thread owns one t.
// ---------------------------------------------------------------------------
__global__ __launch_bounds__(256) void vq_main(
        const float* __restrict__ x,
        const float* __restrict__ cb,
        const float* __restrict__ hcn,
        float* __restrict__ out,
        int* __restrict__ counts,
        double* __restrict__ sse) {

    __shared__ unsigned int hist[C_];
    __shared__ double sred[4];
    for (int i = threadIdx.x; i < C_; i += 256) hist[i] = 0u;
    __syncthreads();

    const int bid  = blockIdx.x;
    const int tile = bid & 7;          // T_/256 = 8 tiles
    const int k    = (bid >> 3) & 7;
    const int b    = bid >> 6;
    const int t    = tile * 256 + threadIdx.x;

    // Load this thread's query column x[b, k*CH..k*CH+63, t] into registers.
    const float* xp = x + ((size_t)(b * D_ + k * CH_)) * T_ + t;
    float xr[CH_];
#pragma unroll
    for (int ch = 0; ch < CH_; ++ch) xr[ch] = xp[(size_t)ch * T_];

    const float* cbk  = cb + (size_t)k * C_ * CH_;
    const float* hck  = hcn + k * C_;

    // fp32 pass: score = 0.5*||c||^2 - x.c  (same argmin as full distance)
    float d1 = INFINITY, d2 = INFINITY;
    int   i1 = 0, i2 = 0;

    for (int c = 0; c < C_; c += 4) {
        const float* p0 = cbk + (size_t)c * CH_;
        float a0 = hck[c + 0];
        float a1 = hck[c + 1];
        float a2 = hck[c + 2];
        float a3 = hck[c + 3];
#pragma unroll
        for (int ch = 0; ch < CH_; ++ch) {
            float xv = xr[ch];
            a0 = fmaf(-xv, p0[ch], a0);
            a1 = fmaf(-xv, p0[CH_ + ch], a1);
            a2 = fmaf(-xv, p0[2 * CH_ + ch], a2);
            a3 = fmaf(-xv, p0[3 * CH_ + ch], a3);
        }
        // Sequential strict-< updates preserve first-occurrence tie-breaks.
#define UPD(dv, cc)                                              \
        {                                                        \
            bool b1 = (dv) < d1;                                 \
            bool b2 = (dv) < d2;                                 \
            float nd1 = b1 ? (dv) : d1;                          \
            int   ni1 = b1 ? (cc) : i1;                          \
            float nd2 = b1 ? d1 : (b2 ? (dv) : d2);              \
            int   ni2 = b1 ? i1 : (b2 ? (cc) : i2);              \
            d1 = nd1; i1 = ni1; d2 = nd2; i2 = ni2;              \
        }
        UPD(a0, c + 0)
        UPD(a1, c + 1)
        UPD(a2, c + 2)
        UPD(a3, c + 3)
#undef UPD
    }

    // fp64 rescore of the two candidates: exact distance sum (x-c)^2.
    const float4* r1 = (const float4*)(cbk + (size_t)i1 * CH_);
    const float4* r2 = (const float4*)(cbk + (size_t)i2 * CH_);
    double s1 = 0.0, s2 = 0.0;
#pragma unroll
    for (int j = 0; j < CH_ / 4; ++j) {
        float4 v1 = r1[j];
        float4 v2 = r2[j];
        double x0 = (double)xr[4 * j + 0];
        double x1 = (double)xr[4 * j + 1];
        double x2 = (double)xr[4 * j + 2];
        double x3 = (double)xr[4 * j + 3];
        double e;
        e = x0 - (double)v1.x; s1 = fma(e, e, s1);
        e = x1 - (double)v1.y; s1 = fma(e, e, s1);
        e = x2 - (double)v1.z; s1 = fma(e, e, s1);
        e = x3 - (double)v1.w; s1 = fma(e, e, s1);
        e = x0 - (double)v2.x; s2 = fma(e, e, s2);
        e = x1 - (double)v2.y; s2 = fma(e, e, s2);
        e = x2 - (double)v2.z; s2 = fma(e, e, s2);
        e = x3 - (double)v2.w; s2 = fma(e, e, s2);
    }
    int idx = (s2 < s1 || (s2 == s1 && i2 < i1)) ? i2 : i1;

    // Write quantized output (coalesced across t) + accumulate SSE.
    float* op = out + ((size_t)(b * D_ + k * CH_)) * T_ + t;
    const float* rq = cbk + (size_t)idx * CH_;
    double local = 0.0;
#pragma unroll
    for (int ch = 0; ch < CH_; ++ch) {
        float qv = rq[ch];
        op[(size_t)ch * T_] = qv;
        double df = (double)xr[ch] - (double)qv;
        local = fma(df, df, local);
    }

    // Histogram (LDS atomics, then sparse flush to global).
    atomicAdd(&hist[idx], 1u);

    // Block-reduce SSE: wave shuffle then LDS.
    for (int off = 32; off > 0; off >>= 1) local += __shfl_down(local, off);
    if ((threadIdx.x & 63) == 0) sred[threadIdx.x >> 6] = local;
    __syncthreads();
    if (threadIdx.x == 0)
        atomicAdd(sse, sred[0] + sred[1] + sred[2] + sred[3]);

    for (int i = threadIdx.x; i < C_; i += 256) {
        unsigned int v = hist[i];
        if (v) atomicAdd(&counts[k * C_ + i], (int)v);
    }
}

// ---------------------------------------------------------------------------
// Kernel C: perplexity per k + commit loss.
// ---------------------------------------------------------------------------
__global__ void vq_final(const int* __restrict__ counts,
                         const double* __restrict__ sse,
                         float* __restrict__ out) {
    __shared__ double part[4];
    const int tid = threadIdx.x;
    for (int k = 0; k < K_; ++k) {
        double local = 0.0;
        for (int j = tid; j < C_; j += 256) {
            double p = (double)counts[k * C_ + j] * (1.0 / (double)(B_ * T_));
            local += -p * log(p + 1e-8);
        }
        for (int off = 32; off > 0; off >>= 1) local += __shfl_down(local, off);
        if ((tid & 63) == 0) part[tid >> 6] = local;
        __syncthreads();
        if (tid == 0) {
            double s = part[0] + part[1] + part[2] + part[3];
            out[QOFF + 1 + k] = (float)exp(s);
        }
        __syncthreads();
    }
    if (tid == 0)
        out[QOFF] = (float)(1.25 * (*sse) / (double)NEL_);
}

// ---------------------------------------------------------------------------
extern "C" void kernel_launch(void* const* d_in, const int* in_sizes, int n_in,
                              void* d_out, int out_size, void* d_ws, size_t ws_size,
                              hipStream_t stream) {
    const float* x  = (const float*)d_in[0];
    const float* cb = (const float*)d_in[1];
    float* out = (float*)d_out;

    float*  hcn    = (float*)((char*)d_ws + WS_HCN);
    int*    counts = (int*)((char*)d_ws + WS_CNT);
    double* sse    = (double*)((char*)d_ws + WS_SSE);

    hipMemsetAsync(d_ws, 0, WS_SSE + 8, stream);

    vq_cnorm<<<(K_ * C_) / 256, 256, 0, stream>>>(cb, hcn);
    vq_main<<<B_ * K_ * (T_ / 256), 256, 0, stream>>>(x, cb, hcn, out, counts, sse);
    vq_final<<<1, 256, 0, stream>>>(counts, sse, out);
}

// Round 2
// 273.668 us; speedup vs baseline: 5.4700x; 5.4700x over previous
//
#include <hip/hip_runtime.h>
#include <hip/hip_bf16.h>
#include <math.h>

// Problem constants
#define B_   16
#define D_   512
#define T_   2048
#define K_   8
#define C_   1024
#define CH_  64
#define NEL_ (B_ * D_ * T_)        // 16777216
#define QOFF 16777216              // out: [quantized | commit | ppl[8]]

// ws layout
#define WS_HCN   0                          // float[K*C]   32 KB  (0.5*||c||^2)
#define WS_CNT   32768                      // int[K*C]     32 KB
#define WS_SSE   65536                      // double       8 B
#define WS_CBH   66048                      // ushort[K*C*CH]  1 MB  bf16(-c) hi
#define WS_CBL   (WS_CBH + K_*C_*CH_*2)     // ushort[K*C*CH]  1 MB  bf16(-c) lo

typedef __attribute__((ext_vector_type(8))) short   short8;
typedef __attribute__((ext_vector_type(8))) __bf16  bf16x8;
typedef __attribute__((ext_vector_type(4))) float   f32x4;

__device__ inline unsigned short f2bf_rne(float f) {
    unsigned u = __builtin_bit_cast(unsigned, f);
    u = u + 0x7FFFu + ((u >> 16) & 1u);
    return (unsigned short)(u >> 16);
}
__device__ inline float bf2f(unsigned short h) {
    unsigned u = ((unsigned)h) << 16;
    return __builtin_bit_cast(float, u);
}

// ---------------------------------------------------------------------------
// Prep: per codebook row, emit bf16 hi/lo split of (-c) and 0.5*||c||^2.
// 8192 rows, one thread per row.
// ---------------------------------------------------------------------------
__global__ void vq_prep(const float* __restrict__ cb,
                        unsigned short* __restrict__ cbh,
                        unsigned short* __restrict__ cbl,
                        float* __restrict__ hcn) {
    int row = blockIdx.x * 256 + threadIdx.x;   // 0..8191
    const float* src = cb + (size_t)row * CH_;
    unsigned short* ph = cbh + (size_t)row * CH_;
    unsigned short* pl = cbl + (size_t)row * CH_;
    float s = 0.f;
#pragma unroll 8
    for (int ch = 0; ch < CH_; ++ch) {
        float v = src[ch];
        s = fmaf(v, v, s);
        float nv = -v;
        unsigned short h = f2bf_rne(nv);
        unsigned short l = f2bf_rne(nv - bf2f(h));
        ph[ch] = h;
        pl[ch] = l;
    }
    hcn[row] = 0.5f * s;
}

// ---------------------------------------------------------------------------
// Main: MFMA scan + argmin + fp64 rescore + quantized write + SSE + counts.
// Block = 256 (4 waves). Wave owns 32 t's of one (b,k). Grid = 16*8*16 = 2048.
// LDS: 64-code chunk, row stride 272 B (16 B pad -> 2-way bank pattern, free).
// ---------------------------------------------------------------------------
#define LDS_ROW 272
#define LDS_HCN_OFF (64 * LDS_ROW)          // 17408
#define LDS_BYTES (LDS_HCN_OFF + 256)

__global__ __launch_bounds__(256) void vq_main(
    const float* __restrict__ x,
    const float* __restrict__ cb,
    const unsigned short* __restrict__ cbh,
    const unsigned short* __restrict__ cbl,
    const float* __restrict__ hcn,
    float* __restrict__ out,
    int* __restrict__ counts,
    double* __restrict__ sse)
{
    __shared__ __align__(16) char lds[LDS_BYTES];
    float* hcnS = (float*)(lds + LDS_HCN_OFF);

    const int tid  = threadIdx.x;
    const int lane = tid & 63;
    const int wave = tid >> 6;
    const int ln   = lane & 15;
    const int q    = lane >> 4;

    const int bid = blockIdx.x;
    const int tc  = bid & 15;
    const int k   = (bid >> 4) & 7;
    const int b   = bid >> 7;
    const int t0  = tc * 128 + wave * 32;

    // ---- Build B fragments (queries), bf16 hi/lo, held in VGPRs ----
    // B[k_dim][n]: n = lane&15 -> t, k_dim = quad*8 + j -> ch (+32 per kstep)
    short8 bh[2][2], bl[2][2];   // [tt][kstep]
    for (int tt = 0; tt < 2; ++tt) {
        int t = t0 + tt * 16 + ln;
        for (int ks = 0; ks < 2; ++ks) {
            const float* xp = x + ((size_t)(b * D_ + k * CH_ + ks * 32 + q * 8)) * T_ + t;
            short8 sh, sl;
#pragma unroll
            for (int j = 0; j < 8; ++j) {
                float v = xp[(size_t)j * T_];
                unsigned short h = f2bf_rne(v);
                unsigned short l = f2bf_rne(v - bf2f(h));
                sh[j] = (short)h;
                sl[j] = (short)l;
            }
            bh[tt][ks] = sh;
            bl[tt][ks] = sl;
        }
    }

    const unsigned short* cbh_k = cbh + (size_t)k * C_ * CH_;
    const unsigned short* cbl_k = cbl + (size_t)k * C_ * CH_;
    const float* hcn_k = hcn + k * C_;

    // Per-slot running minima. Slot (tt, r): c = iter*16 + q*4 + r.
    float md[2][4];
    int   mj[2][4];
#pragma unroll
    for (int tt = 0; tt < 2; ++tt)
#pragma unroll
        for (int r = 0; r < 4; ++r) { md[tt][r] = INFINITY; mj[tt][r] = 0; }

    for (int chunk = 0; chunk < 16; ++chunk) {
        const int c0 = chunk * 64;
        __syncthreads();
        // Stage 64 codebook rows (hi 128B | lo 128B per row) into LDS.
#pragma unroll
        for (int p = 0; p < 4; ++p) {
            int u   = tid + p * 256;
            int row = u >> 4, sub = u & 15;
            const unsigned short* src = (sub < 8)
                ? cbh_k + (size_t)(c0 + row) * CH_ + sub * 8
                : cbl_k + (size_t)(c0 + row) * CH_ + (sub - 8) * 8;
            *(uint4*)(lds + row * LDS_ROW + sub * 16) = *(const uint4*)src;
        }
        if (tid < 64) hcnS[tid] = hcn_k[c0 + tid];
        __syncthreads();

#pragma unroll
        for (int sub = 0; sub < 4; ++sub) {
            const char* base = lds + (sub * 16 + ln) * LDS_ROW;
            f32x4 h4 = *(const f32x4*)(hcnS + sub * 16 + q * 4);   // broadcast
            f32x4 a0 = h4, a1 = h4;
#pragma unroll
            for (int ks = 0; ks < 2; ++ks) {
                bf16x8 ah = __builtin_bit_cast(bf16x8, *(const short8*)(base + ks * 64 + q * 16));
                bf16x8 al = __builtin_bit_cast(bf16x8, *(const short8*)(base + 128 + ks * 64 + q * 16));
                a0 = __builtin_amdgcn_mfma_f32_16x16x32_bf16(ah, __builtin_bit_cast(bf16x8, bh[0][ks]), a0, 0, 0, 0);
                a1 = __builtin_amdgcn_mfma_f32_16x16x32_bf16(ah, __builtin_bit_cast(bf16x8, bh[1][ks]), a1, 0, 0, 0);
                a0 = __builtin_amdgcn_mfma_f32_16x16x32_bf16(ah, __builtin_bit_cast(bf16x8, bl[0][ks]), a0, 0, 0, 0);
                a1 = __builtin_amdgcn_mfma_f32_16x16x32_bf16(ah, __builtin_bit_cast(bf16x8, bl[1][ks]), a1, 0, 0, 0);
                a0 = __builtin_amdgcn_mfma_f32_16x16x32_bf16(al, __builtin_bit_cast(bf16x8, bh[0][ks]), a0, 0, 0, 0);
                a1 = __builtin_amdgcn_mfma_f32_16x16x32_bf16(al, __builtin_bit_cast(bf16x8, bh[1][ks]), a1, 0, 0, 0);
            }
            const int j = chunk * 4 + sub;
#pragma unroll
            for (int r = 0; r < 4; ++r) {
                bool lt0 = a0[r] < md[0][r];
                md[0][r] = lt0 ? a0[r] : md[0][r];
                mj[0][r] = lt0 ? j : mj[0][r];
                bool lt1 = a1[r] < md[1][r];
                md[1][r] = lt1 ? a1[r] : md[1][r];
                mj[1][r] = lt1 ? j : mj[1][r];
            }
        }
    }

    // ---- Epilogue ----
    double waveSse = 0.0;
    const float* cb_k = cb + (size_t)k * C_ * CH_;

    for (int tt = 0; tt < 2; ++tt) {
        const int t = t0 + tt * 16 + ln;

        // Fold 4 slots -> in-lane top-2.
        float d1 = md[tt][0], d2 = INFINITY;
        int   c1 = mj[tt][0] * 16 + q * 4, c2 = 0;
#pragma unroll
        for (int r = 1; r < 4; ++r) {
            float v  = md[tt][r];
            int   cv = mj[tt][r] * 16 + q * 4 + r;
            bool b1 = v < d1;
            bool b2 = v < d2;
            float nd2 = b1 ? d1 : (b2 ? v : d2);
            int   nc2 = b1 ? c1 : (b2 ? cv : c2);
            d1 = b1 ? v : d1;
            c1 = b1 ? cv : c1;
            d2 = nd2; c2 = nc2;
        }
        // Cross-lane top-2 merge over the q dimension (xor 16, 32).
#pragma unroll
        for (int off = 16; off <= 32; off <<= 1) {
            float od1 = __shfl_xor(d1, off);
            int   oc1 = __shfl_xor(c1, off);
            float od2 = __shfl_xor(d2, off);
            int   oc2 = __shfl_xor(c2, off);
            if (od1 < d1) {
                float nd2 = (d1 < od2) ? d1 : od2;
                int   nc2 = (d1 < od2) ? c1 : oc2;
                d1 = od1; c1 = oc1; d2 = nd2; c2 = nc2;
            } else {
                float nd2 = (od1 < d2) ? od1 : d2;
                int   nc2 = (od1 < d2) ? oc1 : c2;
                d2 = nd2; c2 = nc2;
            }
        }

        // fp64 rescore of both candidates, distributed:
        // cand = lane>=32 ? c2 : c1 ; half = (lane>>4)&1 -> 32 ch per lane.
        const int half = q & 1;
        const int cc   = (lane >= 32) ? c2 : c1;
        const float* crow = cb_k + (size_t)cc * CH_ + half * 32;
        const float* xcol = x + ((size_t)(b * D_ + k * CH_ + half * 32)) * T_ + t;
        double s = 0.0;
#pragma unroll
        for (int ch = 0; ch < 32; ++ch) {
            double e = (double)xcol[(size_t)ch * T_] - (double)crow[ch];
            s = fma(e, e, s);
        }
        s += __shfl_xor(s, 16);              // combine halves (same cand)
        double so = __shfl_xor(s, 32);       // other cand's total
        double s1 = (lane < 32) ? s : so;
        double s2 = (lane < 32) ? so : s;
        bool pick2 = (s2 < s1) || (s2 == s1 && c2 < c1);
        int    idx = pick2 ? c2 : c1;
        double dm  = pick2 ? s2 : s1;        // ||x - q||^2 exactly = SSE term

        if (q == 0) {
            waveSse += dm;
            atomicAdd(&counts[k * C_ + idx], 1);
        }

        // Quantized write: lane covers ch = q*16 .. q*16+15, column t.
        const float* qrow = cb_k + (size_t)idx * CH_ + q * 16;
        float* op = out + ((size_t)(b * D_ + k * CH_ + q * 16)) * T_ + t;
#pragma unroll
        for (int jj = 0; jj < 4; ++jj) {
            float4 qv = *(const float4*)(qrow + 4 * jj);
            op[(size_t)(4 * jj + 0) * T_] = qv.x;
            op[(size_t)(4 * jj + 1) * T_] = qv.y;
            op[(size_t)(4 * jj + 2) * T_] = qv.z;
            op[(size_t)(4 * jj + 3) * T_] = qv.w;
        }
    }

    // One fp64 atomic per wave.
    for (int off = 32; off > 0; off >>= 1) waveSse += __shfl_down(waveSse, off);
    if (lane == 0) atomicAdd(sse, waveSse);
}

// ---------------------------------------------------------------------------
// Finalize: perplexity per k + commit loss.
// ---------------------------------------------------------------------------
__global__ void vq_final(const int* __restrict__ counts,
                         const double* __restrict__ sse,
                         float* __restrict__ out) {
    __shared__ double part[4];
    const int tid = threadIdx.x;
    for (int k = 0; k < K_; ++k) {
        double local = 0.0;
        for (int j = tid; j < C_; j += 256) {
            double p = (double)counts[k * C_ + j] * (1.0 / (double)(B_ * T_));
            local += -p * log(p + 1e-8);
        }
        for (int off = 32; off > 0; off >>= 1) local += __shfl_down(local, off);
        if ((tid & 63) == 0) part[tid >> 6] = local;
        __syncthreads();
        if (tid == 0) {
            double sum = part[0] + part[1] + part[2] + part[3];
            out[QOFF + 1 + k] = (float)exp(sum);
        }
        __syncthreads();
    }
    if (tid == 0)
        out[QOFF] = (float)(1.25 * (*sse) / (double)NEL_);
}

// ---------------------------------------------------------------------------
extern "C" void kernel_launch(void* const* d_in, const int* in_sizes, int n_in,
                              void* d_out, int out_size, void* d_ws, size_t ws_size,
                              hipStream_t stream) {
    const float* x  = (const float*)d_in[0];
    const float* cb = (const float*)d_in[1];
    float* out = (float*)d_out;

    float*          hcn    = (float*)((char*)d_ws + WS_HCN);
    int*            counts = (int*)((char*)d_ws + WS_CNT);
    double*         sse    = (double*)((char*)d_ws + WS_SSE);
    unsigned short* cbh    = (unsigned short*)((char*)d_ws + WS_CBH);
    unsigned short* cbl    = (unsigned short*)((char*)d_ws + WS_CBL);

    hipMemsetAsync((char*)d_ws + WS_CNT, 0, 33024, stream);  // counts + sse

    vq_prep<<<(K_ * C_) / 256, 256, 0, stream>>>(cb, cbh, cbl, hcn);
    vq_main<<<B_ * K_ * (T_ / 128), 256, 0, stream>>>(x, cb, cbh, cbl, hcn,
                                                      out, counts, sse);
    vq_final<<<1, 256, 0, stream>>>(counts, sse, out);
}

// Round 6
// 251.248 us; speedup vs baseline: 5.9581x; 1.0892x over previous
//
#include <hip/hip_runtime.h>
#include <hip/hip_bf16.h>
#include <math.h>

// Problem constants
#define B_   16
#define D_   512
#define T_   2048
#define K_   8
#define C_   1024
#define CH_  64
#define NEL_ (B_ * D_ * T_)        // 16777216
#define QOFF 16777216              // out: [quantized | commit | ppl[8]]

// ws layout
#define WS_HCN   0                          // float[K*C]   32 KB (0.5*||c||^2)
#define WS_CNT   32768                      // int[K*C]     32 KB
#define WS_SSE   65536                      // double       8 B
#define WS_CBS   66048                      // swizzled bf16 hi/lo image, 8192 rows * 256 B = 2 MB
// image: row r (= k*1024+c) at WS_CBS + r*256; 16B group s at (s^(r&15))*16
// group s<8: hi bf16 of ch 8s..8s+7 (negated); s>=8: lo bf16 of ch 8(s-8)..

typedef __attribute__((ext_vector_type(8))) short   short8;
typedef __attribute__((ext_vector_type(8))) __bf16  bf16x8;
typedef __attribute__((ext_vector_type(4))) float   f32x4;

__device__ __forceinline__ unsigned short f2bf_rne(float f) {
    unsigned u = __builtin_bit_cast(unsigned, f);
    u = u + 0x7FFFu + ((u >> 16) & 1u);
    return (unsigned short)(u >> 16);
}
__device__ __forceinline__ float bf2f(unsigned short h) {
    unsigned u = ((unsigned)h) << 16;
    return __builtin_bit_cast(float, u);
}

__device__ __forceinline__ void gload_lds16(const void* gsrc, void* ldst) {
    __builtin_amdgcn_global_load_lds(
        (const __attribute__((address_space(1))) unsigned int*)gsrc,
        (__attribute__((address_space(3))) unsigned int*)ldst,
        16, 0, 0);
}

// ---------------------------------------------------------------------------
// Prep: build swizzled bf16 hi/lo image of (-c) + 0.5*||c||^2.
// One thread per 16B group: g = row*16 + s. 131072 threads.
// ---------------------------------------------------------------------------
__global__ void vq_prep(const float* __restrict__ cb,
                        unsigned char* __restrict__ cbS,
                        float* __restrict__ hcn) {
    int g   = blockIdx.x * 256 + threadIdx.x;
    int row = g >> 4;
    int s16 = g & 15;
    const float* src = cb + (size_t)row * CH_;

    int  chBase = (s16 & 7) * 8;
    bool isHi   = s16 < 8;
    short8 val;
#pragma unroll
    for (int j = 0; j < 8; ++j) {
        float v  = src[chBase + j];
        float nv = -v;
        unsigned short h = f2bf_rne(nv);
        val[j] = (short)(isHi ? h : f2bf_rne(nv - bf2f(h)));
    }
    *(short8*)(cbS + (size_t)row * 256 + ((s16 ^ (row & 15)) * 16)) = val;

    if (s16 == 0) {
        float s = 0.f;
#pragma unroll 8
        for (int ch = 0; ch < CH_; ++ch) {
            float v = src[ch];
            s = fmaf(v, v, s);
        }
        hcn[row] = 0.5f * s;
    }
}

// ---------------------------------------------------------------------------
// Main. Block = 256 (4 waves), wave owns 32 t's of one (b,k). Grid = 2048.
// Staging (new, under test): swizzled image, global_load_lds 16B, double buf.
// Argmin + epilogue: ROUND-2 VERBATIM (known-good: md/mj strict-<, xor-merge
// top-2, distributed fp64 rescore, q==0 global atomic counts).
// ---------------------------------------------------------------------------
#define LDSBUF 16384

__global__ __launch_bounds__(256) void vq_main(
    const float* __restrict__ x,
    const float* __restrict__ cb,
    const unsigned char* __restrict__ cbS,
    const float* __restrict__ hcn,
    float* __restrict__ out,
    int* __restrict__ counts,
    double* __restrict__ sse)
{
    __shared__ __align__(16) unsigned char lds[2 * LDSBUF + 4096];
    float* hcnS = (float*)(lds + 2 * LDSBUF);

    const int tid  = threadIdx.x;
    const int lane = tid & 63;
    const int wave = tid >> 6;
    const int ln   = lane & 15;
    const int q    = lane >> 4;
    const int q4   = q * 4;

    const int bid = blockIdx.x;
    const int tc  = bid & 15;
    const int k   = (bid >> 4) & 7;
    const int b   = bid >> 7;
    const int t0  = tc * 128 + wave * 32;

    // ---- B fragments (queries), bf16 hi/lo, in VGPRs (R2 verbatim) ----
    short8 bh[2][2], bl[2][2];   // [tt][kstep]
    for (int tt = 0; tt < 2; ++tt) {
        int t = t0 + tt * 16 + ln;
        for (int ks = 0; ks < 2; ++ks) {
            const float* xp = x + ((size_t)(b * D_ + k * CH_ + ks * 32 + q * 8)) * T_ + t;
            short8 sh, sl;
#pragma unroll
            for (int j = 0; j < 8; ++j) {
                float v = xp[(size_t)j * T_];
                unsigned short h = f2bf_rne(v);
                unsigned short l = f2bf_rne(v - bf2f(h));
                sh[j] = (short)h;
                sl[j] = (short)l;
            }
            bh[tt][ks] = sh;
            bl[tt][ks] = sl;
        }
    }

    const unsigned char* cbS_k = cbS + (size_t)k * C_ * 256;
    const float*         hcn_k = hcn + k * C_;

    // Stage hcn (4 KB) once via plain LDS writes (visible at first barrier).
    for (int i = tid; i < C_; i += 256) hcnS[i] = hcn_k[i];

    // Stage chunk 0 into buf0: each wave 4 x 1 KB async.
    {
        const unsigned char* src = cbS_k + wave * 4096 + lane * 16;
        unsigned char* dst = lds + wave * 4096;
#pragma unroll
        for (int i = 0; i < 4; ++i)
            gload_lds16(src + i * 1024, dst + i * 1024);
    }

    // Per-slot running minima (R2 verbatim). Slot (tt, r): c = j*16 + q*4 + r.
    float md[2][4];
    int   mj[2][4];
#pragma unroll
    for (int tt = 0; tt < 2; ++tt)
#pragma unroll
        for (int r = 0; r < 4; ++r) { md[tt][r] = INFINITY; mj[tt][r] = 0; }

    for (int chunk = 0; chunk < 16; ++chunk) {
        __syncthreads();   // drains this chunk's async loads (+hcnS on iter 0)

        if (chunk < 15) {  // prefetch next chunk into the other buffer
            const unsigned char* src =
                cbS_k + (size_t)(chunk + 1) * 16384 + wave * 4096 + lane * 16;
            unsigned char* dst = lds + ((chunk + 1) & 1) * LDSBUF + wave * 4096;
#pragma unroll
            for (int i = 0; i < 4; ++i)
                gload_lds16(src + i * 1024, dst + i * 1024);
        }

        const unsigned char* buf = lds + (chunk & 1) * LDSBUF;
#pragma unroll
        for (int sub = 0; sub < 4; ++sub) {
            const unsigned char* rowb = buf + (sub * 16 + ln) * 256;
            f32x4 h4 = *(const f32x4*)(hcnS + chunk * 64 + sub * 16 + q4);
            f32x4 a0 = h4, a1 = h4;
#pragma unroll
            for (int ks = 0; ks < 2; ++ks) {
                int cidx = ((ks * 4 + q) ^ ln) * 16;
                bf16x8 ah = __builtin_bit_cast(bf16x8, *(const short8*)(rowb + cidx));
                bf16x8 al = __builtin_bit_cast(bf16x8, *(const short8*)(rowb + (cidx ^ 128)));
                a0 = __builtin_amdgcn_mfma_f32_16x16x32_bf16(ah, __builtin_bit_cast(bf16x8, bh[0][ks]), a0, 0, 0, 0);
                a1 = __builtin_amdgcn_mfma_f32_16x16x32_bf16(ah, __builtin_bit_cast(bf16x8, bh[1][ks]), a1, 0, 0, 0);
                a0 = __builtin_amdgcn_mfma_f32_16x16x32_bf16(ah, __builtin_bit_cast(bf16x8, bl[0][ks]), a0, 0, 0, 0);
                a1 = __builtin_amdgcn_mfma_f32_16x16x32_bf16(ah, __builtin_bit_cast(bf16x8, bl[1][ks]), a1, 0, 0, 0);
                a0 = __builtin_amdgcn_mfma_f32_16x16x32_bf16(al, __builtin_bit_cast(bf16x8, bh[0][ks]), a0, 0, 0, 0);
                a1 = __builtin_amdgcn_mfma_f32_16x16x32_bf16(al, __builtin_bit_cast(bf16x8, bh[1][ks]), a1, 0, 0, 0);
            }
            const int j = chunk * 4 + sub;
#pragma unroll
            for (int r = 0; r < 4; ++r) {
                bool lt0 = a0[r] < md[0][r];
                md[0][r] = lt0 ? a0[r] : md[0][r];
                mj[0][r] = lt0 ? j : mj[0][r];
                bool lt1 = a1[r] < md[1][r];
                md[1][r] = lt1 ? a1[r] : md[1][r];
                mj[1][r] = lt1 ? j : mj[1][r];
            }
        }
    }

    // ---- Epilogue (R2 verbatim) ----
    double waveSse = 0.0;
    const float* cb_k = cb + (size_t)k * C_ * CH_;

    for (int tt = 0; tt < 2; ++tt) {
        const int t = t0 + tt * 16 + ln;

        // Fold 4 slots -> in-lane top-2.
        float d1 = md[tt][0], d2 = INFINITY;
        int   c1 = mj[tt][0] * 16 + q * 4, c2 = 0;
#pragma unroll
        for (int r = 1; r < 4; ++r) {
            float v  = md[tt][r];
            int   cv = mj[tt][r] * 16 + q * 4 + r;
            bool b1 = v < d1;
            bool b2 = v < d2;
            float nd2 = b1 ? d1 : (b2 ? v : d2);
            int   nc2 = b1 ? c1 : (b2 ? cv : c2);
            d1 = b1 ? v : d1;
            c1 = b1 ? cv : c1;
            d2 = nd2; c2 = nc2;
        }
        // Cross-lane top-2 merge over q (xor 16, 32).
#pragma unroll
        for (int off = 16; off <= 32; off <<= 1) {
            float od1 = __shfl_xor(d1, off);
            int   oc1 = __shfl_xor(c1, off);
            float od2 = __shfl_xor(d2, off);
            int   oc2 = __shfl_xor(c2, off);
            if (od1 < d1) {
                float nd2 = (d1 < od2) ? d1 : od2;
                int   nc2 = (d1 < od2) ? c1 : oc2;
                d1 = od1; c1 = oc1; d2 = nd2; c2 = nc2;
            } else {
                float nd2 = (od1 < d2) ? od1 : d2;
                int   nc2 = (od1 < d2) ? oc1 : c2;
                d2 = nd2; c2 = nc2;
            }
        }

        // fp64 rescore of both candidates, distributed over lanes.
        const int half = q & 1;
        const int cc   = (lane >= 32) ? c2 : c1;
        const float* crow = cb_k + (size_t)cc * CH_ + half * 32;
        const float* xcol = x + ((size_t)(b * D_ + k * CH_ + half * 32)) * T_ + t;
        double s = 0.0;
#pragma unroll
        for (int ch = 0; ch < 32; ++ch) {
            double e = (double)xcol[(size_t)ch * T_] - (double)crow[ch];
            s = fma(e, e, s);
        }
        s += __shfl_xor(s, 16);              // combine halves (same cand)
        double so = __shfl_xor(s, 32);       // other cand's total
        double s1 = (lane < 32) ? s : so;
        double s2 = (lane < 32) ? so : s;
        bool pick2 = (s2 < s1) || (s2 == s1 && c2 < c1);
        int    idx = pick2 ? c2 : c1;
        double dm  = pick2 ? s2 : s1;        // ||x - q||^2 = SSE term

        if (q == 0) {
            waveSse += dm;
            atomicAdd(&counts[k * C_ + idx], 1);
        }

        // Quantized write: lane covers ch = q*16 .. q*16+15, column t.
        const float* qrow = cb_k + (size_t)idx * CH_ + q * 16;
        float* op = out + ((size_t)(b * D_ + k * CH_ + q * 16)) * T_ + t;
#pragma unroll
        for (int jj = 0; jj < 4; ++jj) {
            float4 qv = *(const float4*)(qrow + 4 * jj);
            op[(size_t)(4 * jj + 0) * T_] = qv.x;
            op[(size_t)(4 * jj + 1) * T_] = qv.y;
            op[(size_t)(4 * jj + 2) * T_] = qv.z;
            op[(size_t)(4 * jj + 3) * T_] = qv.w;
        }
    }

    // One fp64 atomic per wave.
    for (int off = 32; off > 0; off >>= 1) waveSse += __shfl_down(waveSse, off);
    if (lane == 0) atomicAdd(sse, waveSse);
}

// ---------------------------------------------------------------------------
// Finalize: one block per k -> perplexity; block 0 also writes commit loss.
// ---------------------------------------------------------------------------
__global__ void vq_final(const int* __restrict__ counts,
                         const double* __restrict__ sse,
                         float* __restrict__ out) {
    __shared__ double part[4];
    const int tid = threadIdx.x;
    const int k   = blockIdx.x;
    double local = 0.0;
    for (int j = tid; j < C_; j += 256) {
        double p = (double)counts[k * C_ + j] * (1.0 / (double)(B_ * T_));
        local += -p * log(p + 1e-8);
    }
    for (int off = 32; off > 0; off >>= 1) local += __shfl_down(local, off);
    if ((tid & 63) == 0) part[tid >> 6] = local;
    __syncthreads();
    if (tid == 0) {
        double sum = part[0] + part[1] + part[2] + part[3];
        out[QOFF + 1 + k] = (float)exp(sum);
        if (k == 0)
            out[QOFF] = (float)(1.25 * (*sse) / (double)NEL_);
    }
}

// ---------------------------------------------------------------------------
extern "C" void kernel_launch(void* const* d_in, const int* in_sizes, int n_in,
                              void* d_out, int out_size, void* d_ws, size_t ws_size,
                              hipStream_t stream) {
    const float* x  = (const float*)d_in[0];
    const float* cb = (const float*)d_in[1];
    float* out = (float*)d_out;

    float*         hcn    = (float*)((char*)d_ws + WS_HCN);
    int*           counts = (int*)((char*)d_ws + WS_CNT);
    double*        sse    = (double*)((char*)d_ws + WS_SSE);
    unsigned char* cbS    = (unsigned char*)((char*)d_ws + WS_CBS);

    hipMemsetAsync((char*)d_ws + WS_CNT, 0, 33024, stream);  // counts + sse

    vq_prep<<<(K_ * C_ * 16) / 256, 256, 0, stream>>>(cb, cbS, hcn);
    vq_main<<<B_ * K_ * (T_ / 128), 256, 0, stream>>>(x, cb, cbS, hcn,
                                                      out, counts, sse);
    vq_final<<<K_, 256, 0, stream>>>(counts, sse, out);
}